// Round 1
// baseline (564.916 us; speedup 1.0000x reference)
//
#include <hip/hip_runtime.h>

typedef __attribute__((ext_vector_type(8))) _Float16 f16x8;
typedef __attribute__((ext_vector_type(4))) float f32x4;
typedef _Float16 half_t;

#define MFMA16(a, b, c) __builtin_amdgcn_mfma_f32_16x16x32_f16((a), (b), (c), 0, 0, 0)

// B=4, S=4096, D=256 fixed for this problem.

// ---------------- projection: out[s][e] = sum_d X[s][d]*W[e][d] + bias[e], fp16 out ----
__global__ __launch_bounds__(512, 2)
void proj_kernel(const float* __restrict__ X, const float* __restrict__ W,
                 const float* __restrict__ bias, half_t* __restrict__ out)
{
    __shared__ half_t Wl[256 * 264];   // padded stride 264 (528B) -> ~2-way banks
    int tid = threadIdx.x;
    for (int i = 0; i < 128; ++i) {    // 512 thr * 128 = 65536 elements
        int idx = tid + i * 512;
        int r = idx >> 8, c = idx & 255;
        Wl[r * 264 + c] = (half_t)W[idx];
    }
    __syncthreads();

    int w = tid >> 6, lane = tid & 63, l15 = lane & 15, hi = lane >> 4;
    int row0 = blockIdx.x * 128 + w * 16;   // 128 blocks * 128 rows = 16384 rows

    const float* xb = X + (size_t)(row0 + l15) * 256 + hi * 8;
    f32x4 acc[16];
#pragma unroll
    for (int n = 0; n < 16; ++n) acc[n] = (f32x4){0.f, 0.f, 0.f, 0.f};

#pragma unroll
    for (int kd = 0; kd < 8; ++kd) {
        const float4* xv = (const float4*)(xb + kd * 32);
        float4 x0 = xv[0], x1 = xv[1];
        f16x8 a = { (half_t)x0.x, (half_t)x0.y, (half_t)x0.z, (half_t)x0.w,
                    (half_t)x1.x, (half_t)x1.y, (half_t)x1.z, (half_t)x1.w };
#pragma unroll
        for (int n = 0; n < 16; ++n) {
            f16x8 bf = *(const f16x8*)&Wl[(n * 16 + l15) * 264 + kd * 32 + hi * 8];
            acc[n] = MFMA16(a, bf, acc[n]);
        }
    }

#pragma unroll
    for (int n = 0; n < 16; ++n) {
        float bv = bias[n * 16 + l15];
#pragma unroll
        for (int r = 0; r < 4; ++r) {
            float v = acc[n][r] + bv;
            out[(size_t)(row0 + 4 * hi + r) * 256 + n * 16 + l15] = (half_t)v;
        }
    }
}

// ---------------- V transpose: vt[b][d][s] = (fp16) V[b][s][d] ----------------
__global__ __launch_bounds__(256)
void vt_kernel(const float* __restrict__ V, half_t* __restrict__ vt)
{
    __shared__ half_t tile[64][65];
    int tid = threadIdx.x;
    int b = blockIdx.x >> 8, rest = blockIdx.x & 255;
    int s0 = (rest >> 2) * 64, d0 = (rest & 3) * 64;
#pragma unroll
    for (int i = 0; i < 16; ++i) {
        int srow = i * 4 + (tid >> 6);
        int dcol = tid & 63;
        tile[srow][dcol] = (half_t)V[(size_t)(b * 4096 + s0 + srow) * 256 + d0 + dcol];
    }
    __syncthreads();
#pragma unroll
    for (int i = 0; i < 16; ++i) {
        int drow = i * 4 + (tid >> 6);
        int scol = tid & 63;
        vt[(size_t)(b * 256 + d0 + drow) * 4096 + s0 + scol] = tile[scol][drow];
    }
}

// ---------------- fused attention: 16 q-rows per block, 8 waves x 512 k-cols ----------
__global__ __launch_bounds__(512, 2)
void attn_kernel(const half_t* __restrict__ qh, const half_t* __restrict__ kh,
                 const half_t* __restrict__ vt, const int* __restrict__ mask,
                 float* __restrict__ ctx_out, float* __restrict__ attn_out)
{
    __shared__ half_t attn_lds[8][8192];   // 128 KiB: per-wave 16x512 fp16 attn slice
    __shared__ float redbuf[2][16][8];     // cross-wave max/sum

    int tid = threadIdx.x;
    int w = tid >> 6, lane = tid & 63, l15 = lane & 15, hi = lane >> 4;
    int b = blockIdx.x >> 8, qt = blockIdx.x & 255, q0 = qt * 16;

    // ---- Q fragments (16 rows x 256 d), A-layout: row=l15, k=hi*8+j ----
    f16x8 qf[8];
    const half_t* qb = qh + (size_t)(b * 4096 + q0 + l15) * 256 + hi * 8;
#pragma unroll
    for (int kd = 0; kd < 8; ++kd) qf[kd] = *(const f16x8*)(qb + kd * 32);

    // ---- QK^T: wave w covers k-cols [w*512, w*512+512) in 32 tiles of 16 ----
    f32x4 sc[32];
    const half_t* kbase = kh + (size_t)(b * 4096 + w * 512 + l15) * 256 + hi * 8;
#pragma unroll
    for (int ct = 0; ct < 32; ++ct) {
        f32x4 c = {0.f, 0.f, 0.f, 0.f};
        const half_t* kb = kbase + (size_t)ct * 16 * 256;
#pragma unroll
        for (int kd = 0; kd < 8; ++kd) {
            f16x8 kf = *(const f16x8*)(kb + kd * 32);
            c = MFMA16(qf[kd], kf, c);
        }
        sc[ct] = c * 0.0625f;   // 1/sqrt(256)
    }

    // ---- mask: row masked (False) -> all scores 0 -> uniform softmax = 1/4096 ----
    bool km[4];
#pragma unroll
    for (int r = 0; r < 4; ++r) km[r] = mask[b * 4096 + q0 + 4 * hi + r] != 0;
#pragma unroll
    for (int ct = 0; ct < 32; ++ct)
#pragma unroll
        for (int r = 0; r < 4; ++r)
            if (!km[r]) sc[ct][r] = 0.f;

    // ---- row max: per-lane over 32 cols, then 16-lane group, then cross-wave ----
    float vmax[4];
#pragma unroll
    for (int r = 0; r < 4; ++r) vmax[r] = sc[0][r];
#pragma unroll
    for (int ct = 1; ct < 32; ++ct)
#pragma unroll
        for (int r = 0; r < 4; ++r) vmax[r] = fmaxf(vmax[r], sc[ct][r]);
#pragma unroll
    for (int off = 1; off < 16; off <<= 1)
#pragma unroll
        for (int r = 0; r < 4; ++r) vmax[r] = fmaxf(vmax[r], __shfl_xor(vmax[r], off, 64));
    if (l15 == 0) {
#pragma unroll
        for (int r = 0; r < 4; ++r) redbuf[0][4 * hi + r][w] = vmax[r];
    }
    __syncthreads();
    float m_[4];
#pragma unroll
    for (int r = 0; r < 4; ++r) {
        float mm = redbuf[0][4 * hi + r][0];
#pragma unroll
        for (int ww = 1; ww < 8; ++ww) mm = fmaxf(mm, redbuf[0][4 * hi + r][ww]);
        m_[r] = mm;
    }

    // ---- exp + row sum ----
    float vsum[4] = {0.f, 0.f, 0.f, 0.f};
#pragma unroll
    for (int ct = 0; ct < 32; ++ct)
#pragma unroll
        for (int r = 0; r < 4; ++r) {
            float p = __expf(sc[ct][r] - m_[r]);
            sc[ct][r] = p;
            vsum[r] += p;
        }
#pragma unroll
    for (int off = 1; off < 16; off <<= 1)
#pragma unroll
        for (int r = 0; r < 4; ++r) vsum[r] += __shfl_xor(vsum[r], off, 64);
    if (l15 == 0) {
#pragma unroll
        for (int r = 0; r < 4; ++r) redbuf[1][4 * hi + r][w] = vsum[r];
    }
    __syncthreads();
    float inv_[4];
#pragma unroll
    for (int r = 0; r < 4; ++r) {
        float ss = redbuf[1][4 * hi + r][0];
#pragma unroll
        for (int ww = 1; ww < 8; ++ww) ss += redbuf[1][4 * hi + r][ww];
        inv_[r] = 1.0f / ss;
    }

    // ---- write attn (f32, HBM) + stash fp16 copy in XOR-swizzled LDS ----
    float* aout = attn_out + ((size_t)(b * 4096) + q0) * 4096 + w * 512;
    char* slice = (char*)&attn_lds[w][0];
#pragma unroll
    for (int ct = 0; ct < 32; ++ct)
#pragma unroll
        for (int r = 0; r < 4; ++r) {
            int row = 4 * hi + r, col = ct * 16 + l15;
            float a = sc[ct][r] * inv_[r];
            aout[(size_t)row * 4096 + col] = a;
            int byte = (row * 1024 + col * 2) ^ ((row & 7) << 4);
            *(half_t*)(slice + byte) = (half_t)a;
        }
    __syncthreads();

    // ---- PV: context partial [16 x 256] per wave over its 512 k-cols ----
    f32x4 acc[16];
#pragma unroll
    for (int n = 0; n < 16; ++n) acc[n] = (f32x4){0.f, 0.f, 0.f, 0.f};
    const half_t* vtb = vt + (size_t)(b * 256 + l15) * 4096 + w * 512 + hi * 8;
#pragma unroll
    for (int kd = 0; kd < 16; ++kd) {
        int byte = (l15 * 1024 + kd * 64 + hi * 16) ^ ((l15 & 7) << 4);
        f16x8 af = *(const f16x8*)(slice + byte);
        const half_t* vb = vtb + kd * 32;
#pragma unroll
        for (int n = 0; n < 16; ++n) {
            f16x8 bf = *(const f16x8*)(vb + (size_t)n * 16 * 4096);
            acc[n] = MFMA16(af, bf, acc[n]);
        }
    }
    __syncthreads();

    // ---- cross-wave reduce of context partials via LDS (reuse attn_lds) ----
    float* cp = (float*)&attn_lds[w][0];   // 16 KiB slice = 16x256 f32
#pragma unroll
    for (int n = 0; n < 16; ++n)
#pragma unroll
        for (int r = 0; r < 4; ++r)
            cp[(4 * hi + r) * 256 + n * 16 + l15] = acc[n][r];
    __syncthreads();

    for (int e = tid; e < 4096; e += 512) {
        int row = e >> 8, col = e & 255;
        float s = 0.f;
#pragma unroll
        for (int ww = 0; ww < 8; ++ww) s += ((float*)&attn_lds[ww][0])[row * 256 + col];
        ctx_out[(size_t)(b * 4096 + q0 + row) * 256 + col] = s;
    }
}

extern "C" void kernel_launch(void* const* d_in, const int* in_sizes, int n_in,
                              void* d_out, int out_size, void* d_ws, size_t ws_size,
                              hipStream_t stream) {
    const float* query = (const float*)d_in[0];
    const float* key   = (const float*)d_in[1];
    const float* value = (const float*)d_in[2];
    const int*   mask  = (const int*)d_in[3];
    const float* Wq    = (const float*)d_in[4];
    const float* bq    = (const float*)d_in[5];
    const float* Wk    = (const float*)d_in[6];
    const float* bk    = (const float*)d_in[7];

    float* ctx  = (float*)d_out;                       // [4,4096,256]
    float* attn = ctx + (size_t)4 * 4096 * 256;        // [4,4096,4096]

    half_t* qh = (half_t*)d_ws;                        // 8 MB
    half_t* kh = qh + (size_t)4 * 4096 * 256;          // 8 MB
    half_t* vt = kh + (size_t)4 * 4096 * 256;          // 8 MB

    proj_kernel<<<128, 512, 0, stream>>>(query, Wq, bq, qh);
    proj_kernel<<<128, 512, 0, stream>>>(key,   Wk, bk, kh);
    vt_kernel<<<1024, 256, 0, stream>>>(value, vt);
    attn_kernel<<<1024, 512, 0, stream>>>(qh, kh, vt, mask, ctx, attn);
}